// Round 10
// baseline (380.018 us; speedup 1.0000x reference)
//
#include <hip/hip_runtime.h>

// MultiLayerGCN on MI355X — round 10: R8 baseline + gather fused into MLP.
// k_gmlp: per 64-node block, aggregate (wave-per-node, same as k_gather) ->
// rows into swizzled LDS -> A-frags to regs -> overlay LDS with Wh staging ->
// R8's proven MLP chunk loop. Removes actb round-trip + 2 dispatch drains,
// overlaps latency-bound gather blocks with MFMA-bound MLP blocks.
// Math: t2 = (relu((Anorm@x)@W1+b1))@W2                  [k_gmlp FIRST]
//       out = relu(relu((relu(Anorm@t2+b2))@W3+b3)@W4+b4) [k_gmlp second]
// Anorm@y [d] = sum_{e: dst=d} nrm[e]*y[src(e)] + y[d]*dinv[d]^2

#define ELLW 64

typedef short bf16x8 __attribute__((ext_vector_type(8)));
typedef float f32x4 __attribute__((ext_vector_type(4)));

__device__ __forceinline__ unsigned short f2b(float f) {
    unsigned u = __builtin_bit_cast(unsigned, f);
    unsigned r = (u + 0x7FFFu + ((u >> 16) & 1u)) >> 16;
    return (unsigned short)r;
}
__device__ __forceinline__ float b2f(unsigned short u) {
    return __builtin_bit_cast(float, (unsigned)u << 16);
}

// merged setup: zero cnt | 4x weight transpose fp32->bf16T | x -> bf16
// block ranges: [0,196) cnt, [196,1476) weights, [1476,7726) x   (R8 version)
__global__ void k_setup(const float* __restrict__ x,
                        const float* __restrict__ W1, const float* __restrict__ W2,
                        const float* __restrict__ W3, const float* __restrict__ W4,
                        unsigned short* __restrict__ W1t, unsigned short* __restrict__ W2t,
                        unsigned short* __restrict__ W3t, unsigned short* __restrict__ W4t,
                        unsigned short* __restrict__ xb, int* __restrict__ cnt, int Nn) {
    int b = blockIdx.x;
    if (b < 196) {
        int i = b * 256 + threadIdx.x;
        if (i < Nn) cnt[i] = 0;
    } else if (b < 1476) {
        int i = (b - 196) * 256 + threadIdx.x;
        if (i < 65536) {                       // W1: 128x512
            int k = i >> 9, n = i & 511;
            W1t[n * 128 + k] = f2b(W1[i]);
        } else if (i < 131072) {               // W2: 512x128
            int j = i - 65536; int k = j >> 7, n = j & 127;
            W2t[n * 512 + k] = f2b(W2[j]);
        } else if (i < 262144) {               // W3: 128x1024
            int j = i - 131072; int k = j >> 10, n = j & 1023;
            W3t[n * 128 + k] = f2b(W3[j]);
        } else {                               // W4: 1024x64
            int j = i - 262144; int k = j >> 6, n = j & 63;
            W4t[n * 1024 + k] = f2b(W4[j]);
        }
    } else {
        int i = (b - 1476) * 256 + threadIdx.x;
        if (i < Nn * 32) {
            float4 v = ((const float4*)x)[i];
            ushort4 o;
            o.x = f2b(v.x); o.y = f2b(v.y); o.z = f2b(v.z); o.w = f2b(v.w);
            ((ushort4*)xb)[i] = o;
        }
    }
}

// one atomic + one 8B store per edge: record = (src, bits(w))
__global__ void k_fill_ell(const int* __restrict__ src, const int* __restrict__ dst,
                           const float* __restrict__ w, int* __restrict__ cnt,
                           int2* __restrict__ s_edge, int E) {
    int e = blockIdx.x * 256 + threadIdx.x;
    if (e >= E) return;
    int d = dst[e];
    int2 rec = make_int2(src[e], __builtin_bit_cast(int, w[e]));
    int slot = atomicAdd(&cnt[d], 1);
    if (slot < ELLW) s_edge[(size_t)d * ELLW + slot] = rec;
}

// one wave per node: dinv[node] = rsqrt(1 + sum_j w_j)   (no atomics)
__global__ __launch_bounds__(256) void k_deg(const int2* __restrict__ s_edge,
                                             const int* __restrict__ cnt,
                                             float* __restrict__ dinv, int Nn) {
    int node = blockIdx.x * 4 + (threadIdx.x >> 6);
    if (node >= Nn) return;
    int lane = threadIdx.x & 63;
    int c = min(cnt[node], ELLW);
    float s = 0.0f;
    if (lane < c) s = __builtin_bit_cast(float, s_edge[(size_t)node * ELLW + lane].y);
    #pragma unroll
    for (int d = 32; d > 0; d >>= 1) s += __shfl_down(s, d);
    if (lane == 0) dinv[node] = rsqrtf(1.0f + s);
}

// Fused gather + 2-layer MLP. Per 64-node block (4 waves, 16 nodes/wave):
//   Phase A (gather, = k_gather): agg row per node via shuffle-broadcast ELL
//     loop; optional +agg_bias,relu; bf16 rows -> swizzled LDS (wave-private).
//   A-frags -> regs; ONE barrier; overlay LDS with Wh staging.
//   Phase B (= R8 k_mlp): per 64-hidden chunk: MFMA-h, bias+relu -> Ps
//     (wave-private), MFMA-o accumulate; 2 barriers/chunk staging Whs+Wos.
// FIRST: compute nrm = dinv[src]*w*dinv[node], write back into record.y.
template <int H, int OUTW, bool FIRST, bool AGG_BIAS, bool HAS_BO, bool OUT_BF16>
__global__ __launch_bounds__(256) void k_gmlp(
    const unsigned short* __restrict__ Xb, int2* __restrict__ s_edge,
    const int* __restrict__ cnt, const float* __restrict__ dinv,
    const float* __restrict__ agg_bias,
    const unsigned short* __restrict__ Wht, const unsigned short* __restrict__ Wot,
    const float* __restrict__ bh, const float* __restrict__ bo,
    void* __restrict__ out, int Nn) {
    constexpr int HC = H / 64;            // hidden chunks
    constexpr int NJ = OUTW / 16;         // out col tiles
    constexpr int OW4 = OUTW / 32;        // int4/thread for Wo chunk staging
    __shared__ __align__(16) unsigned short AWhs[64 * 128]; // 16 KB: A rows, then Whs
    __shared__ __align__(16) unsigned short Ps[64 * 64];    // 8 KB (wave-private rows)
    __shared__ __align__(16) unsigned short Wos[OUTW * 64]; // 8/16 KB
    const int tid = threadIdx.x, wave = tid >> 6, lane = tid & 63;
    const int lm = lane & 15, quad = lane >> 4;
    const int bm0 = blockIdx.x * 64;

    // ---- Phase A: aggregate this wave's 16 nodes into AWhs rows ----
    for (int t = 0; t < 16; ++t) {
        int row = wave * 16 + t;          // local row
        int node = bm0 + row;
        float ax = 0.0f, ay = 0.0f;
        if (node < Nn) {
            float di = dinv[node];
            float dii = di * di;
            ushort2 sv = ((const ushort2*)(Xb + (size_t)node * 128))[lane];
            ax = b2f(sv.x) * dii; ay = b2f(sv.y) * dii;

            int c = min(cnt[node], ELLW);
            size_t base = (size_t)node * ELLW;
            int sreg = 0;
            float nv = 0.0f;
            if (lane < c) {
                int2 rec = s_edge[base + lane];
                sreg = rec.x;
                if (FIRST) {
                    float wv = __builtin_bit_cast(float, rec.y);
                    nv = dinv[sreg] * wv * di;
                    ((int*)s_edge)[2 * (base + lane) + 1] = __builtin_bit_cast(int, nv);
                } else {
                    nv = __builtin_bit_cast(float, rec.y);
                }
            }
            int j = 0;
            for (; j + 8 <= c; j += 8) {
                int s0 = __shfl(sreg, j),     s1 = __shfl(sreg, j + 1);
                int s2 = __shfl(sreg, j + 2), s3 = __shfl(sreg, j + 3);
                int s4 = __shfl(sreg, j + 4), s5 = __shfl(sreg, j + 5);
                int s6 = __shfl(sreg, j + 6), s7 = __shfl(sreg, j + 7);
                float n0 = __shfl(nv, j),     n1 = __shfl(nv, j + 1);
                float n2 = __shfl(nv, j + 2), n3 = __shfl(nv, j + 3);
                float n4 = __shfl(nv, j + 4), n5 = __shfl(nv, j + 5);
                float n6 = __shfl(nv, j + 6), n7 = __shfl(nv, j + 7);
                ushort2 r0 = ((const ushort2*)(Xb + (size_t)s0 * 128))[lane];
                ushort2 r1 = ((const ushort2*)(Xb + (size_t)s1 * 128))[lane];
                ushort2 r2 = ((const ushort2*)(Xb + (size_t)s2 * 128))[lane];
                ushort2 r3 = ((const ushort2*)(Xb + (size_t)s3 * 128))[lane];
                ushort2 r4 = ((const ushort2*)(Xb + (size_t)s4 * 128))[lane];
                ushort2 r5 = ((const ushort2*)(Xb + (size_t)s5 * 128))[lane];
                ushort2 r6 = ((const ushort2*)(Xb + (size_t)s6 * 128))[lane];
                ushort2 r7 = ((const ushort2*)(Xb + (size_t)s7 * 128))[lane];
                ax += n0 * b2f(r0.x) + n1 * b2f(r1.x) + n2 * b2f(r2.x) + n3 * b2f(r3.x);
                ay += n0 * b2f(r0.y) + n1 * b2f(r1.y) + n2 * b2f(r2.y) + n3 * b2f(r3.y);
                ax += n4 * b2f(r4.x) + n5 * b2f(r5.x) + n6 * b2f(r6.x) + n7 * b2f(r7.x);
                ay += n4 * b2f(r4.y) + n5 * b2f(r5.y) + n6 * b2f(r6.y) + n7 * b2f(r7.y);
            }
            for (; j < c; ++j) {
                int sj = __shfl(sreg, j);
                float nj = __shfl(nv, j);
                ushort2 r = ((const ushort2*)(Xb + (size_t)sj * 128))[lane];
                ax += nj * b2f(r.x);
                ay += nj * b2f(r.y);
            }
            if (AGG_BIAS) {
                float2 bv = ((const float2*)agg_bias)[lane];
                ax = fmaxf(ax + bv.x, 0.0f);
                ay = fmaxf(ay + bv.y, 0.0f);
            }
        }
        // write row to LDS (wave-private), swizzled like the Whs layout
        int col = 2 * lane;
        int g = col >> 3;
        ushort2 o; o.x = f2b(ax); o.y = f2b(ay);
        *(ushort2*)&AWhs[row * 128 + ((g ^ (row & 15)) * 8) + (col & 7)] = o;
    }

    // A-fragments to regs (wave-private rows -> no barrier needed)
    bf16x8 af[4];
    {
        int r = wave * 16 + lm;
        #pragma unroll
        for (int kb = 0; kb < 4; ++kb) {
            int g = kb * 4 + quad;
            af[kb] = *(const bf16x8*)&AWhs[r * 128 + ((g ^ (r & 15)) * 8)];
        }
    }
    __syncthreads();   // everyone done with A rows; safe to overlay with Whs

    // ---- Phase B: R8 MLP loop ----
    // stage chunk 0
    #pragma unroll
    for (int u = 0; u < 4; ++u) {
        int idx = tid + u * 256; int r = idx >> 4, g = idx & 15;
        *(int4*)&AWhs[r * 128 + ((g ^ (r & 15)) * 8)] =
            *(const int4*)(Wht + (size_t)r * 128 + g * 8);
    }
    #pragma unroll
    for (int u = 0; u < OW4; ++u) {
        int idx = tid + u * 256; int r = idx >> 3, g = idx & 7;
        *(int4*)&Wos[r * 64 + ((g ^ (r & 7)) * 8)] =
            *(const int4*)(Wot + (size_t)r * H + g * 8);
    }
    __syncthreads();

    f32x4 oacc[NJ] = {};
    for (int c = 0; c < HC; ++c) {
        // GEMM-h: 16 rows x 64 hidden cols
        f32x4 hacc[4] = {};
        #pragma unroll
        for (int kb = 0; kb < 4; ++kb) {
            bf16x8 bfr[4];
            #pragma unroll
            for (int j = 0; j < 4; ++j) {
                int r = j * 16 + lm, g = kb * 4 + quad;
                bfr[j] = *(const bf16x8*)&AWhs[r * 128 + ((g ^ (r & 15)) * 8)];
            }
            #pragma unroll
            for (int j = 0; j < 4; ++j)
                hacc[j] = __builtin_amdgcn_mfma_f32_16x16x32_bf16(af[kb], bfr[j], hacc[j], 0, 0, 0);
        }

        // epilogue -> Ps (wave-private rows; no barrier needed)
        #pragma unroll
        for (int j = 0; j < 4; ++j) {
            int col = j * 16 + lm;
            float bv = bh[c * 64 + col];
            #pragma unroll
            for (int r4 = 0; r4 < 4; ++r4) {
                int row = wave * 16 + quad * 4 + r4;
                float o = fmaxf(hacc[j][r4] + bv, 0.0f);
                Ps[row * 64 + (((col >> 3) ^ (row & 7)) * 8) + (col & 7)] = f2b(o);
            }
        }

        // GEMM-o: accumulate 16 rows x OUTW cols
        #pragma unroll
        for (int kb = 0; kb < 2; ++kb) {
            bf16x8 pf;
            {
                int r = wave * 16 + lm, g = kb * 4 + quad;
                pf = *(const bf16x8*)&Ps[r * 64 + ((g ^ (r & 7)) * 8)];
            }
            #pragma unroll
            for (int j = 0; j < NJ; ++j) {
                int r = j * 16 + lm, g = kb * 4 + quad;
                bf16x8 wf = *(const bf16x8*)&Wos[r * 64 + ((g ^ (r & 7)) * 8)];
                oacc[j] = __builtin_amdgcn_mfma_f32_16x16x32_bf16(pf, wf, oacc[j], 0, 0, 0);
            }
        }

        if (c + 1 < HC) {
            __syncthreads();   // all waves done reading Whs/Wos
            #pragma unroll
            for (int u = 0; u < 4; ++u) {
                int idx = tid + u * 256; int r = idx >> 4, g = idx & 15;
                *(int4*)&AWhs[r * 128 + ((g ^ (r & 15)) * 8)] =
                    *(const int4*)(Wht + (size_t)((c + 1) * 64 + r) * 128 + g * 8);
            }
            #pragma unroll
            for (int u = 0; u < OW4; ++u) {
                int idx = tid + u * 256; int r = idx >> 3, g = idx & 7;
                *(int4*)&Wos[r * 64 + ((g ^ (r & 7)) * 8)] =
                    *(const int4*)(Wot + (size_t)r * H + (c + 1) * 64 + g * 8);
            }
            __syncthreads();   // staging visible before next chunk's reads
        }
    }

    // final epilogue
    #pragma unroll
    for (int j = 0; j < NJ; ++j) {
        int col = j * 16 + lm;
        float bv = HAS_BO ? bo[col] : 0.0f;
        #pragma unroll
        for (int r4 = 0; r4 < 4; ++r4) {
            int m = bm0 + wave * 16 + quad * 4 + r4;
            if (m < Nn) {
                float o = oacc[j][r4];
                if (HAS_BO) o = fmaxf(o + bv, 0.0f);
                if (OUT_BF16)
                    ((unsigned short*)out)[(size_t)m * OUTW + col] = f2b(o);
                else
                    ((float*)out)[(size_t)m * OUTW + col] = o;
            }
        }
    }
}

static inline int cdiv(long a, long b) { return (int)((a + b - 1) / b); }

extern "C" void kernel_launch(void* const* d_in, const int* in_sizes, int n_in,
                              void* d_out, int out_size, void* d_ws, size_t ws_size,
                              hipStream_t stream) {
    const float* x  = (const float*)d_in[0];
    const int*   ei = (const int*)d_in[1];
    const float* ew = (const float*)d_in[2];
    const float* W1 = (const float*)d_in[3];
    const float* b1 = (const float*)d_in[4];
    const float* W2 = (const float*)d_in[5];
    const float* b2 = (const float*)d_in[6];
    const float* W3 = (const float*)d_in[7];
    const float* b3 = (const float*)d_in[8];
    const float* W4 = (const float*)d_in[9];
    const float* b4 = (const float*)d_in[10];
    const int Nn = in_sizes[0] / 128;   // 50000
    const int E  = in_sizes[1] / 2;     // 800000
    const int* src = ei;
    const int* dst = ei + E;

    char* ws = (char*)d_ws;
    size_t off_b = 0;
    auto alloc = [&](size_t bytes) -> void* {
        void* p = ws + off_b;
        off_b += (bytes + 255) & ~(size_t)255;
        return p;
    };
    float*          dinv   = (float*)alloc((size_t)Nn * 4);
    int*            cnt    = (int*)alloc((size_t)Nn * 4);
    int2*           s_edge = (int2*)alloc((size_t)Nn * ELLW * 8);    // 25.6 MB, (src, w->nrm)
    unsigned short* W1t    = (unsigned short*)alloc(512 * 128 * 2);
    unsigned short* W2t    = (unsigned short*)alloc(128 * 512 * 2);
    unsigned short* W3t    = (unsigned short*)alloc(1024 * 128 * 2);
    unsigned short* W4t    = (unsigned short*)alloc(64 * 1024 * 2);
    unsigned short* xb     = (unsigned short*)alloc((size_t)Nn * 128 * 2);
    unsigned short* t2b    = (unsigned short*)alloc((size_t)Nn * 128 * 2);
    float*          out    = (float*)d_out;

    // setup (zero cnt | weight transposes | x->bf16), ELL build, deg
    k_setup<<<7726, 256, 0, stream>>>(x, W1, W2, W3, W4, W1t, W2t, W3t, W4t, xb, cnt, Nn);
    k_fill_ell<<<cdiv(E, 256), 256, 0, stream>>>(src, dst, ew, cnt, s_edge, E);
    k_deg<<<cdiv(Nn, 4), 256, 0, stream>>>(s_edge, cnt, dinv, Nn);

    // fused: agg1 (computes+stores nrm) + layers 1+2 -> t2 (bf16)
    k_gmlp<512, 128, true, false, false, true><<<cdiv(Nn, 64), 256, 0, stream>>>(
        xb, s_edge, cnt, dinv, nullptr, W1t, W2t, b1, nullptr, t2b, Nn);

    // fused: agg2 (+b2+relu) + layers 3+4 -> out (fp32)
    k_gmlp<1024, 64, false, true, true, false><<<cdiv(Nn, 64), 256, 0, stream>>>(
        t2b, s_edge, cnt, dinv, b2, W3t, W4t, b3, b4, out, Nn);
}

// Round 11
// 358.232 us; speedup vs baseline: 1.0608x; 1.0608x over previous
//
#include <hip/hip_runtime.h>

// MultiLayerGCN on MI355X — round 11: de-confounded recombination.
// R9's merged setup+fill_ell (measured win) + R8's k_mlp with Wos removed
// (Wo fragments direct from L2-resident global; LDS 24 KB -> 6 blocks/CU).
// Grid/wave structure of every kernel identical to R8 (the proven baseline).
// Math: agg1 = Anorm@x;  t2 = (relu(agg1@W1+b1))@W2      [k_mlp, H=512]
//       h2 = relu(Anorm@t2 + b2)
//       out = relu(relu(h2@W3+b3)@W4+b4)                 [k_mlp, H=1024]
// Anorm@y [d] = sum_{e: dst=d} nrm[e]*y[src(e)] + y[d]*dinv[d]^2

#define ELLW 64

typedef short bf16x8 __attribute__((ext_vector_type(8)));
typedef float f32x4 __attribute__((ext_vector_type(4)));

__device__ __forceinline__ unsigned short f2b(float f) {
    unsigned u = __builtin_bit_cast(unsigned, f);
    unsigned r = (u + 0x7FFFu + ((u >> 16) & 1u)) >> 16;
    return (unsigned short)r;
}
__device__ __forceinline__ float b2f(unsigned short u) {
    return __builtin_bit_cast(float, (unsigned)u << 16);
}

// merged setup: ELL fill (atomics, latency-bound) | weight transposes | x->bf16.
// Block ranges: [0,3125) fill, [3125,4405) weights, [4405,10655) x.
// cnt must be zeroed (hipMemsetAsync) before this kernel.
__global__ void k_setup(const float* __restrict__ x,
                        const float* __restrict__ W1, const float* __restrict__ W2,
                        const float* __restrict__ W3, const float* __restrict__ W4,
                        unsigned short* __restrict__ W1t, unsigned short* __restrict__ W2t,
                        unsigned short* __restrict__ W3t, unsigned short* __restrict__ W4t,
                        unsigned short* __restrict__ xb,
                        const int* __restrict__ src, const int* __restrict__ dst,
                        const float* __restrict__ ew, int* __restrict__ cnt,
                        int2* __restrict__ s_edge, int Nn, int E) {
    int b = blockIdx.x;
    if (b < 3125) {
        int e = b * 256 + threadIdx.x;
        if (e < E) {
            int d = dst[e];
            int2 rec = make_int2(src[e], __builtin_bit_cast(int, ew[e]));
            int slot = atomicAdd(&cnt[d], 1);
            if (slot < ELLW) s_edge[(size_t)d * ELLW + slot] = rec;
        }
    } else if (b < 4405) {
        int i = (b - 3125) * 256 + threadIdx.x;
        if (i < 65536) {                       // W1: 128x512
            int k = i >> 9, n = i & 511;
            W1t[n * 128 + k] = f2b(W1[i]);
        } else if (i < 131072) {               // W2: 512x128
            int j = i - 65536; int k = j >> 7, n = j & 127;
            W2t[n * 512 + k] = f2b(W2[j]);
        } else if (i < 262144) {               // W3: 128x1024
            int j = i - 131072; int k = j >> 10, n = j & 1023;
            W3t[n * 128 + k] = f2b(W3[j]);
        } else {                               // W4: 1024x64
            int j = i - 262144; int k = j >> 6, n = j & 63;
            W4t[n * 1024 + k] = f2b(W4[j]);
        }
    } else {
        int i = (b - 4405) * 256 + threadIdx.x;
        if (i < Nn * 32) {
            float4 v = ((const float4*)x)[i];
            ushort4 o;
            o.x = f2b(v.x); o.y = f2b(v.y); o.z = f2b(v.z); o.w = f2b(v.w);
            ((ushort4*)xb)[i] = o;
        }
    }
}

// one wave per node: dinv[node] = rsqrt(1 + sum_j w_j)   (no atomics)
__global__ __launch_bounds__(256) void k_deg(const int2* __restrict__ s_edge,
                                             const int* __restrict__ cnt,
                                             float* __restrict__ dinv, int Nn) {
    int node = blockIdx.x * 4 + (threadIdx.x >> 6);
    if (node >= Nn) return;
    int lane = threadIdx.x & 63;
    int c = min(cnt[node], ELLW);
    float s = 0.0f;
    if (lane < c) s = __builtin_bit_cast(float, s_edge[(size_t)node * ELLW + lane].y);
    #pragma unroll
    for (int d = 32; d > 0; d >>= 1) s += __shfl_down(s, d);
    if (lane == 0) dinv[node] = rsqrtf(1.0f + s);
}

// one wave per node; lane j<c holds edge j's (src, nrm) in regs, broadcast via shfl.
// FIRST: compute nrm = dinv[src]*w*dinv[node], write back into record.y.
template <bool FIRST, bool BIAS_RELU>
__global__ __launch_bounds__(256) void k_gather(
    const unsigned short* __restrict__ Xb, int2* __restrict__ s_edge,
    const int* __restrict__ cnt, const float* __restrict__ dinv,
    const float* __restrict__ bias, unsigned short* __restrict__ outb, int Nn) {
    int node = blockIdx.x * 4 + (threadIdx.x >> 6);
    if (node >= Nn) return;
    int lane = threadIdx.x & 63;
    float di = dinv[node];
    float dii = di * di;
    ushort2 sv = ((const ushort2*)(Xb + (size_t)node * 128))[lane];
    float ax = b2f(sv.x) * dii, ay = b2f(sv.y) * dii;

    int c = min(cnt[node], ELLW);
    size_t base = (size_t)node * ELLW;
    int sreg = 0;
    float nv = 0.0f;
    if (lane < c) {
        int2 rec = s_edge[base + lane];
        sreg = rec.x;
        if (FIRST) {
            float wv = __builtin_bit_cast(float, rec.y);
            nv = dinv[sreg] * wv * di;
            ((int*)s_edge)[2 * (base + lane) + 1] = __builtin_bit_cast(int, nv);
        } else {
            nv = __builtin_bit_cast(float, rec.y);
        }
    }

    int j = 0;
    for (; j + 8 <= c; j += 8) {
        int s0 = __shfl(sreg, j),     s1 = __shfl(sreg, j + 1);
        int s2 = __shfl(sreg, j + 2), s3 = __shfl(sreg, j + 3);
        int s4 = __shfl(sreg, j + 4), s5 = __shfl(sreg, j + 5);
        int s6 = __shfl(sreg, j + 6), s7 = __shfl(sreg, j + 7);
        float n0 = __shfl(nv, j),     n1 = __shfl(nv, j + 1);
        float n2 = __shfl(nv, j + 2), n3 = __shfl(nv, j + 3);
        float n4 = __shfl(nv, j + 4), n5 = __shfl(nv, j + 5);
        float n6 = __shfl(nv, j + 6), n7 = __shfl(nv, j + 7);
        ushort2 r0 = ((const ushort2*)(Xb + (size_t)s0 * 128))[lane];
        ushort2 r1 = ((const ushort2*)(Xb + (size_t)s1 * 128))[lane];
        ushort2 r2 = ((const ushort2*)(Xb + (size_t)s2 * 128))[lane];
        ushort2 r3 = ((const ushort2*)(Xb + (size_t)s3 * 128))[lane];
        ushort2 r4 = ((const ushort2*)(Xb + (size_t)s4 * 128))[lane];
        ushort2 r5 = ((const ushort2*)(Xb + (size_t)s5 * 128))[lane];
        ushort2 r6 = ((const ushort2*)(Xb + (size_t)s6 * 128))[lane];
        ushort2 r7 = ((const ushort2*)(Xb + (size_t)s7 * 128))[lane];
        ax += n0 * b2f(r0.x) + n1 * b2f(r1.x) + n2 * b2f(r2.x) + n3 * b2f(r3.x);
        ay += n0 * b2f(r0.y) + n1 * b2f(r1.y) + n2 * b2f(r2.y) + n3 * b2f(r3.y);
        ax += n4 * b2f(r4.x) + n5 * b2f(r5.x) + n6 * b2f(r6.x) + n7 * b2f(r7.x);
        ay += n4 * b2f(r4.y) + n5 * b2f(r5.y) + n6 * b2f(r6.y) + n7 * b2f(r7.y);
    }
    for (; j < c; ++j) {
        int sj = __shfl(sreg, j);
        float nj = __shfl(nv, j);
        ushort2 r = ((const ushort2*)(Xb + (size_t)sj * 128))[lane];
        ax += nj * b2f(r.x);
        ay += nj * b2f(r.y);
    }

    if (BIAS_RELU) {
        float2 bv = ((const float2*)bias)[lane];
        ax = fmaxf(ax + bv.x, 0.0f);
        ay = fmaxf(ay + bv.y, 0.0f);
    }
    ushort2 o; o.x = f2b(ax); o.y = f2b(ay);
    ((ushort2*)(outb + (size_t)node * 128))[lane] = o;
}

// Fused 2-layer MLP: out = g2(g1(A@Wh + bh) @ Wo [+ bo]), g1 = relu,
// g2 = relu iff HAS_BO. A: [M][128] bf16; Wht: [H][128]; Wot: [OUTW][H].
// 64 rows/block, 4 waves (16 rows each) — R8 structure. A-frags in regs;
// Wh chunks staged in LDS (2 barriers/chunk); Wo fragments DIRECT from
// global (L2-resident, no Wos buffer). P wave-private in LDS (no barrier).
// LDS = 24 KB -> 6 blocks/CU. XOR-swizzled LDS: 2-way max (free).
template <int H, int OUTW, bool HAS_BO, bool OUT_BF16>
__global__ __launch_bounds__(256) void k_mlp(
    const unsigned short* __restrict__ A, const unsigned short* __restrict__ Wht,
    const unsigned short* __restrict__ Wot, const float* __restrict__ bh,
    const float* __restrict__ bo, void* __restrict__ out, int M) {
    constexpr int HC = H / 64;            // hidden chunks
    constexpr int NJ = OUTW / 16;         // out col tiles
    __shared__ __align__(16) unsigned short Whs[64 * 128];   // 16 KB
    __shared__ __align__(16) unsigned short Ps[64 * 64];     // 8 KB (wave-private rows)
    const int tid = threadIdx.x, wave = tid >> 6, lane = tid & 63;
    const int lm = lane & 15, quad = lane >> 4;
    const int bm0 = blockIdx.x * 64;

    // A-fragments in registers (read once)
    bf16x8 af[4];
    {
        int gr = bm0 + wave * 16 + lm;
        #pragma unroll
        for (int kb = 0; kb < 4; ++kb) af[kb] = bf16x8{0, 0, 0, 0, 0, 0, 0, 0};
        if (gr < M) {
            #pragma unroll
            for (int kb = 0; kb < 4; ++kb)
                af[kb] = *(const bf16x8*)(A + (size_t)gr * 128 + kb * 32 + quad * 8);
        }
    }

    // stage Wh chunk 0
    #pragma unroll
    for (int u = 0; u < 4; ++u) {
        int idx = tid + u * 256; int r = idx >> 4, g = idx & 15;
        *(int4*)&Whs[r * 128 + ((g ^ (r & 15)) * 8)] =
            *(const int4*)(Wht + (size_t)r * 128 + g * 8);
    }
    __syncthreads();

    f32x4 oacc[NJ] = {};
    for (int c = 0; c < HC; ++c) {
        // GEMM-h: 16 rows x 64 hidden cols
        f32x4 hacc[4] = {};
        #pragma unroll
        for (int kb = 0; kb < 4; ++kb) {
            bf16x8 bfr[4];
            #pragma unroll
            for (int j = 0; j < 4; ++j) {
                int r = j * 16 + lm, g = kb * 4 + quad;
                bfr[j] = *(const bf16x8*)&Whs[r * 128 + ((g ^ (r & 15)) * 8)];
            }
            #pragma unroll
            for (int j = 0; j < 4; ++j)
                hacc[j] = __builtin_amdgcn_mfma_f32_16x16x32_bf16(af[kb], bfr[j], hacc[j], 0, 0, 0);
        }

        // epilogue -> Ps (wave-private rows; no barrier needed)
        #pragma unroll
        for (int j = 0; j < 4; ++j) {
            int col = j * 16 + lm;
            float bv = bh[c * 64 + col];
            #pragma unroll
            for (int r4 = 0; r4 < 4; ++r4) {
                int row = wave * 16 + quad * 4 + r4;
                float o = fmaxf(hacc[j][r4] + bv, 0.0f);
                Ps[row * 64 + (((col >> 3) ^ (row & 7)) * 8) + (col & 7)] = f2b(o);
            }
        }

        // GEMM-o: accumulate 16 rows x OUTW cols; Wo direct from global (L2)
        #pragma unroll
        for (int kb = 0; kb < 2; ++kb) {
            bf16x8 pf;
            {
                int r = wave * 16 + lm, g = kb * 4 + quad;
                pf = *(const bf16x8*)&Ps[r * 64 + ((g ^ (r & 7)) * 8)];
            }
            #pragma unroll
            for (int j = 0; j < NJ; ++j) {
                bf16x8 wf = *(const bf16x8*)(Wot + (size_t)(j * 16 + lm) * H +
                                             c * 64 + kb * 32 + quad * 8);
                oacc[j] = __builtin_amdgcn_mfma_f32_16x16x32_bf16(pf, wf, oacc[j], 0, 0, 0);
            }
        }

        if (c + 1 < HC) {
            __syncthreads();   // all waves done reading Whs
            #pragma unroll
            for (int u = 0; u < 4; ++u) {
                int idx = tid + u * 256; int r = idx >> 4, g = idx & 15;
                *(int4*)&Whs[r * 128 + ((g ^ (r & 15)) * 8)] =
                    *(const int4*)(Wht + (size_t)((c + 1) * 64 + r) * 128 + g * 8);
            }
            __syncthreads();   // staging visible before next chunk's reads
        }
    }

    // final epilogue
    #pragma unroll
    for (int j = 0; j < NJ; ++j) {
        int col = j * 16 + lm;
        float bv = HAS_BO ? bo[col] : 0.0f;
        #pragma unroll
        for (int r4 = 0; r4 < 4; ++r4) {
            int m = bm0 + wave * 16 + quad * 4 + r4;
            if (m < M) {
                float o = oacc[j][r4];
                if (HAS_BO) o = fmaxf(o + bv, 0.0f);
                if (OUT_BF16)
                    ((unsigned short*)out)[(size_t)m * OUTW + col] = f2b(o);
                else
                    ((float*)out)[(size_t)m * OUTW + col] = o;
            }
        }
    }
}

static inline int cdiv(long a, long b) { return (int)((a + b - 1) / b); }

extern "C" void kernel_launch(void* const* d_in, const int* in_sizes, int n_in,
                              void* d_out, int out_size, void* d_ws, size_t ws_size,
                              hipStream_t stream) {
    const float* x  = (const float*)d_in[0];
    const int*   ei = (const int*)d_in[1];
    const float* ew = (const float*)d_in[2];
    const float* W1 = (const float*)d_in[3];
    const float* b1 = (const float*)d_in[4];
    const float* W2 = (const float*)d_in[5];
    const float* b2 = (const float*)d_in[6];
    const float* W3 = (const float*)d_in[7];
    const float* b3 = (const float*)d_in[8];
    const float* W4 = (const float*)d_in[9];
    const float* b4 = (const float*)d_in[10];
    const int Nn = in_sizes[0] / 128;   // 50000
    const int E  = in_sizes[1] / 2;     // 800000
    const int* src = ei;
    const int* dst = ei + E;

    char* ws = (char*)d_ws;
    size_t off_b = 0;
    auto alloc = [&](size_t bytes) -> void* {
        void* p = ws + off_b;
        off_b += (bytes + 255) & ~(size_t)255;
        return p;
    };
    float*          dinv   = (float*)alloc((size_t)Nn * 4);
    int*            cnt    = (int*)alloc((size_t)Nn * 4);
    int2*           s_edge = (int2*)alloc((size_t)Nn * ELLW * 8);    // 25.6 MB, (src, w->nrm)
    unsigned short* W1t    = (unsigned short*)alloc(512 * 128 * 2);
    unsigned short* W2t    = (unsigned short*)alloc(128 * 512 * 2);
    unsigned short* W3t    = (unsigned short*)alloc(1024 * 128 * 2);
    unsigned short* W4t    = (unsigned short*)alloc(64 * 1024 * 2);
    unsigned short* xb     = (unsigned short*)alloc((size_t)Nn * 128 * 2);
    unsigned short* t2b    = (unsigned short*)alloc((size_t)Nn * 128 * 2);
    unsigned short* actb   = (unsigned short*)alloc((size_t)Nn * 128 * 2);
    float*          out    = (float*)d_out;

    // zero ELL counters, then merged setup (fill_ell | weights | x->bf16)
    hipMemsetAsync(cnt, 0, (size_t)Nn * 4, stream);
    k_setup<<<10655, 256, 0, stream>>>(x, W1, W2, W3, W4, W1t, W2t, W3t, W4t,
                                       xb, src, dst, ew, cnt, s_edge, Nn, E);
    k_deg<<<cdiv(Nn, 4), 256, 0, stream>>>(s_edge, cnt, dinv, Nn);

    // agg1 = Anorm@x (computes+stores nrm), fused layers 1+2 -> t2 (bf16)
    k_gather<true, false><<<cdiv(Nn, 4), 256, 0, stream>>>(
        xb, s_edge, cnt, dinv, nullptr, actb, Nn);
    k_mlp<512, 128, false, true><<<cdiv(Nn, 64), 256, 0, stream>>>(
        actb, W1t, W2t, b1, nullptr, t2b, Nn);

    // h2 = relu(Anorm@t2 + b2)
    k_gather<false, true><<<cdiv(Nn, 4), 256, 0, stream>>>(
        t2b, s_edge, cnt, dinv, b2, actb, Nn);

    // fused layers 3+4 -> out (fp32)
    k_mlp<1024, 64, true, false><<<cdiv(Nn, 64), 256, 0, stream>>>(
        actb, W3t, W4t, b3, b4, out, Nn);
}

// Round 12
// 289.412 us; speedup vs baseline: 1.3131x; 1.2378x over previous
//
#include <hip/hip_runtime.h>

// MultiLayerGCN on MI355X — round 12: merged setup+fill (R11, measured -10us)
// + k_mlp 128 rows/block, 32 rows/wave with Wos STAGED in LDS (R9's tiling
// minus its direct-global-Wo penalty, which R11 measured at +24us/kernel).
// Per chunk per wave: 16 Whs ds_read feed 32 MFMA (was 16) — halves the
// LDS-pipe cost per FLOP that bounds R8's mlp.
// Math: agg1 = Anorm@x;  t2 = (relu(agg1@W1+b1))@W2      [k_mlp, H=512]
//       h2 = relu(Anorm@t2 + b2)
//       out = relu(relu(h2@W3+b3)@W4+b4)                 [k_mlp, H=1024]
// Anorm@y [d] = sum_{e: dst=d} nrm[e]*y[src(e)] + y[d]*dinv[d]^2

#define ELLW 64

typedef short bf16x8 __attribute__((ext_vector_type(8)));
typedef float f32x4 __attribute__((ext_vector_type(4)));

__device__ __forceinline__ unsigned short f2b(float f) {
    unsigned u = __builtin_bit_cast(unsigned, f);
    unsigned r = (u + 0x7FFFu + ((u >> 16) & 1u)) >> 16;
    return (unsigned short)r;
}
__device__ __forceinline__ float b2f(unsigned short u) {
    return __builtin_bit_cast(float, (unsigned)u << 16);
}

// merged setup: ELL fill (atomics, latency-bound) | weight transposes | x->bf16.
// Block ranges: [0,3125) fill, [3125,4405) weights, [4405,10655) x.
// cnt must be zeroed (hipMemsetAsync) before this kernel.
__global__ void k_setup(const float* __restrict__ x,
                        const float* __restrict__ W1, const float* __restrict__ W2,
                        const float* __restrict__ W3, const float* __restrict__ W4,
                        unsigned short* __restrict__ W1t, unsigned short* __restrict__ W2t,
                        unsigned short* __restrict__ W3t, unsigned short* __restrict__ W4t,
                        unsigned short* __restrict__ xb,
                        const int* __restrict__ src, const int* __restrict__ dst,
                        const float* __restrict__ ew, int* __restrict__ cnt,
                        int2* __restrict__ s_edge, int Nn, int E) {
    int b = blockIdx.x;
    if (b < 3125) {
        int e = b * 256 + threadIdx.x;
        if (e < E) {
            int d = dst[e];
            int2 rec = make_int2(src[e], __builtin_bit_cast(int, ew[e]));
            int slot = atomicAdd(&cnt[d], 1);
            if (slot < ELLW) s_edge[(size_t)d * ELLW + slot] = rec;
        }
    } else if (b < 4405) {
        int i = (b - 3125) * 256 + threadIdx.x;
        if (i < 65536) {                       // W1: 128x512
            int k = i >> 9, n = i & 511;
            W1t[n * 128 + k] = f2b(W1[i]);
        } else if (i < 131072) {               // W2: 512x128
            int j = i - 65536; int k = j >> 7, n = j & 127;
            W2t[n * 512 + k] = f2b(W2[j]);
        } else if (i < 262144) {               // W3: 128x1024
            int j = i - 131072; int k = j >> 10, n = j & 1023;
            W3t[n * 128 + k] = f2b(W3[j]);
        } else {                               // W4: 1024x64
            int j = i - 262144; int k = j >> 6, n = j & 63;
            W4t[n * 1024 + k] = f2b(W4[j]);
        }
    } else {
        int i = (b - 4405) * 256 + threadIdx.x;
        if (i < Nn * 32) {
            float4 v = ((const float4*)x)[i];
            ushort4 o;
            o.x = f2b(v.x); o.y = f2b(v.y); o.z = f2b(v.z); o.w = f2b(v.w);
            ((ushort4*)xb)[i] = o;
        }
    }
}

// one wave per node: dinv[node] = rsqrt(1 + sum_j w_j)   (no atomics)
__global__ __launch_bounds__(256) void k_deg(const int2* __restrict__ s_edge,
                                             const int* __restrict__ cnt,
                                             float* __restrict__ dinv, int Nn) {
    int node = blockIdx.x * 4 + (threadIdx.x >> 6);
    if (node >= Nn) return;
    int lane = threadIdx.x & 63;
    int c = min(cnt[node], ELLW);
    float s = 0.0f;
    if (lane < c) s = __builtin_bit_cast(float, s_edge[(size_t)node * ELLW + lane].y);
    #pragma unroll
    for (int d = 32; d > 0; d >>= 1) s += __shfl_down(s, d);
    if (lane == 0) dinv[node] = rsqrtf(1.0f + s);
}

// one wave per node; lane j<c holds edge j's (src, nrm) in regs, broadcast via shfl.
// FIRST: compute nrm = dinv[src]*w*dinv[node], write back into record.y.
template <bool FIRST, bool BIAS_RELU>
__global__ __launch_bounds__(256) void k_gather(
    const unsigned short* __restrict__ Xb, int2* __restrict__ s_edge,
    const int* __restrict__ cnt, const float* __restrict__ dinv,
    const float* __restrict__ bias, unsigned short* __restrict__ outb, int Nn) {
    int node = blockIdx.x * 4 + (threadIdx.x >> 6);
    if (node >= Nn) return;
    int lane = threadIdx.x & 63;
    float di = dinv[node];
    float dii = di * di;
    ushort2 sv = ((const ushort2*)(Xb + (size_t)node * 128))[lane];
    float ax = b2f(sv.x) * dii, ay = b2f(sv.y) * dii;

    int c = min(cnt[node], ELLW);
    size_t base = (size_t)node * ELLW;
    int sreg = 0;
    float nv = 0.0f;
    if (lane < c) {
        int2 rec = s_edge[base + lane];
        sreg = rec.x;
        if (FIRST) {
            float wv = __builtin_bit_cast(float, rec.y);
            nv = dinv[sreg] * wv * di;
            ((int*)s_edge)[2 * (base + lane) + 1] = __builtin_bit_cast(int, nv);
        } else {
            nv = __builtin_bit_cast(float, rec.y);
        }
    }

    int j = 0;
    for (; j + 8 <= c; j += 8) {
        int s0 = __shfl(sreg, j),     s1 = __shfl(sreg, j + 1);
        int s2 = __shfl(sreg, j + 2), s3 = __shfl(sreg, j + 3);
        int s4 = __shfl(sreg, j + 4), s5 = __shfl(sreg, j + 5);
        int s6 = __shfl(sreg, j + 6), s7 = __shfl(sreg, j + 7);
        float n0 = __shfl(nv, j),     n1 = __shfl(nv, j + 1);
        float n2 = __shfl(nv, j + 2), n3 = __shfl(nv, j + 3);
        float n4 = __shfl(nv, j + 4), n5 = __shfl(nv, j + 5);
        float n6 = __shfl(nv, j + 6), n7 = __shfl(nv, j + 7);
        ushort2 r0 = ((const ushort2*)(Xb + (size_t)s0 * 128))[lane];
        ushort2 r1 = ((const ushort2*)(Xb + (size_t)s1 * 128))[lane];
        ushort2 r2 = ((const ushort2*)(Xb + (size_t)s2 * 128))[lane];
        ushort2 r3 = ((const ushort2*)(Xb + (size_t)s3 * 128))[lane];
        ushort2 r4 = ((const ushort2*)(Xb + (size_t)s4 * 128))[lane];
        ushort2 r5 = ((const ushort2*)(Xb + (size_t)s5 * 128))[lane];
        ushort2 r6 = ((const ushort2*)(Xb + (size_t)s6 * 128))[lane];
        ushort2 r7 = ((const ushort2*)(Xb + (size_t)s7 * 128))[lane];
        ax += n0 * b2f(r0.x) + n1 * b2f(r1.x) + n2 * b2f(r2.x) + n3 * b2f(r3.x);
        ay += n0 * b2f(r0.y) + n1 * b2f(r1.y) + n2 * b2f(r2.y) + n3 * b2f(r3.y);
        ax += n4 * b2f(r4.x) + n5 * b2f(r5.x) + n6 * b2f(r6.x) + n7 * b2f(r7.x);
        ay += n4 * b2f(r4.y) + n5 * b2f(r5.y) + n6 * b2f(r6.y) + n7 * b2f(r7.y);
    }
    for (; j < c; ++j) {
        int sj = __shfl(sreg, j);
        float nj = __shfl(nv, j);
        ushort2 r = ((const ushort2*)(Xb + (size_t)sj * 128))[lane];
        ax += nj * b2f(r.x);
        ay += nj * b2f(r.y);
    }

    if (BIAS_RELU) {
        float2 bv = ((const float2*)bias)[lane];
        ax = fmaxf(ax + bv.x, 0.0f);
        ay = fmaxf(ay + bv.y, 0.0f);
    }
    ushort2 o; o.x = f2b(ax); o.y = f2b(ay);
    ((ushort2*)(outb + (size_t)node * 128))[lane] = o;
}

// Fused 2-layer MLP: out = g2(g1(A@Wh + bh) @ Wo [+ bo]), g1 = relu,
// g2 = relu iff HAS_BO. A: [M][128] bf16; Wht: [H][128]; Wot: [OUTW][H].
// 128 rows/block, 4 waves x 32 rows (16 Whs ds_reads feed 32 MFMA).
// A-frags in regs; Wh + Wo chunks staged in LDS, 2 barriers/chunk (R8
// staging). P wave-private in LDS (no barrier). XOR-swizzle: 2-way max.
template <int H, int OUTW, bool HAS_BO, bool OUT_BF16>
__global__ __launch_bounds__(256) void k_mlp(
    const unsigned short* __restrict__ A, const unsigned short* __restrict__ Wht,
    const unsigned short* __restrict__ Wot, const float* __restrict__ bh,
    const float* __restrict__ bo, void* __restrict__ out, int M) {
    constexpr int HC = H / 64;            // hidden chunks
    constexpr int NJ = OUTW / 16;         // out col tiles
    constexpr int OW4 = OUTW / 32;        // int4/thread for Wo chunk staging
    __shared__ __align__(16) unsigned short Whs[64 * 128];   // 16 KB
    __shared__ __align__(16) unsigned short Ps[128 * 64];    // 16 KB (wave-private rows)
    __shared__ __align__(16) unsigned short Wos[OUTW * 64];  // 8/16 KB
    const int tid = threadIdx.x, wave = tid >> 6, lane = tid & 63;
    const int lm = lane & 15, quad = lane >> 4;
    const int bm0 = blockIdx.x * 128;

    // A-fragments in registers (read once): 2 row-tiles of 16
    bf16x8 af[2][4];
    #pragma unroll
    for (int i = 0; i < 2; ++i) {
        int gr = bm0 + wave * 32 + i * 16 + lm;
        #pragma unroll
        for (int kb = 0; kb < 4; ++kb) af[i][kb] = bf16x8{0, 0, 0, 0, 0, 0, 0, 0};
        if (gr < M) {
            #pragma unroll
            for (int kb = 0; kb < 4; ++kb)
                af[i][kb] = *(const bf16x8*)(A + (size_t)gr * 128 + kb * 32 + quad * 8);
        }
    }

    // stage chunk 0 (Wh + Wo)
    #pragma unroll
    for (int u = 0; u < 4; ++u) {
        int idx = tid + u * 256; int r = idx >> 4, g = idx & 15;
        *(int4*)&Whs[r * 128 + ((g ^ (r & 15)) * 8)] =
            *(const int4*)(Wht + (size_t)r * 128 + g * 8);
    }
    #pragma unroll
    for (int u = 0; u < OW4; ++u) {
        int idx = tid + u * 256; int r = idx >> 3, g = idx & 7;
        *(int4*)&Wos[r * 64 + ((g ^ (r & 7)) * 8)] =
            *(const int4*)(Wot + (size_t)r * H + g * 8);
    }
    __syncthreads();

    f32x4 oacc[2][NJ] = {};
    for (int c = 0; c < HC; ++c) {
        // GEMM-h: 32 rows x 64 hidden cols (16 ds_read -> 32 MFMA)
        f32x4 hacc[2][4] = {};
        #pragma unroll
        for (int kb = 0; kb < 4; ++kb) {
            bf16x8 bfr[4];
            #pragma unroll
            for (int j = 0; j < 4; ++j) {
                int r = j * 16 + lm, g = kb * 4 + quad;
                bfr[j] = *(const bf16x8*)&Whs[r * 128 + ((g ^ (r & 15)) * 8)];
            }
            #pragma unroll
            for (int i = 0; i < 2; ++i)
                #pragma unroll
                for (int j = 0; j < 4; ++j)
                    hacc[i][j] = __builtin_amdgcn_mfma_f32_16x16x32_bf16(
                        af[i][kb], bfr[j], hacc[i][j], 0, 0, 0);
        }

        // epilogue -> Ps (wave-private rows; no barrier needed)
        #pragma unroll
        for (int i = 0; i < 2; ++i) {
            #pragma unroll
            for (int j = 0; j < 4; ++j) {
                int col = j * 16 + lm;
                float bv = bh[c * 64 + col];
                #pragma unroll
                for (int r4 = 0; r4 < 4; ++r4) {
                    int row = wave * 32 + i * 16 + quad * 4 + r4;
                    float o = fmaxf(hacc[i][j][r4] + bv, 0.0f);
                    Ps[row * 64 + (((col >> 3) ^ (row & 7)) * 8) + (col & 7)] = f2b(o);
                }
            }
        }

        // GEMM-o: accumulate 32 rows x OUTW cols from staged Wos
        #pragma unroll
        for (int kb = 0; kb < 2; ++kb) {
            bf16x8 pf[2];
            #pragma unroll
            for (int i = 0; i < 2; ++i) {
                int r = wave * 32 + i * 16 + lm, g = kb * 4 + quad;
                pf[i] = *(const bf16x8*)&Ps[r * 64 + ((g ^ (r & 7)) * 8)];
            }
            #pragma unroll
            for (int j = 0; j < NJ; ++j) {
                int r = j * 16 + lm, g = kb * 4 + quad;
                bf16x8 wf = *(const bf16x8*)&Wos[r * 64 + ((g ^ (r & 7)) * 8)];
                #pragma unroll
                for (int i = 0; i < 2; ++i)
                    oacc[i][j] = __builtin_amdgcn_mfma_f32_16x16x32_bf16(
                        pf[i], wf, oacc[i][j], 0, 0, 0);
            }
        }

        if (c + 1 < HC) {
            __syncthreads();   // all waves done reading Whs/Wos
            #pragma unroll
            for (int u = 0; u < 4; ++u) {
                int idx = tid + u * 256; int r = idx >> 4, g = idx & 15;
                *(int4*)&Whs[r * 128 + ((g ^ (r & 15)) * 8)] =
                    *(const int4*)(Wht + (size_t)((c + 1) * 64 + r) * 128 + g * 8);
            }
            #pragma unroll
            for (int u = 0; u < OW4; ++u) {
                int idx = tid + u * 256; int r = idx >> 3, g = idx & 7;
                *(int4*)&Wos[r * 64 + ((g ^ (r & 7)) * 8)] =
                    *(const int4*)(Wot + (size_t)r * H + (c + 1) * 64 + g * 8);
            }
            __syncthreads();   // staging visible before next chunk's reads
        }
    }

    // final epilogue
    #pragma unroll
    for (int i = 0; i < 2; ++i) {
        #pragma unroll
        for (int j = 0; j < NJ; ++j) {
            int col = j * 16 + lm;
            float bv = HAS_BO ? bo[col] : 0.0f;
            #pragma unroll
            for (int r4 = 0; r4 < 4; ++r4) {
                int m = bm0 + wave * 32 + i * 16 + quad * 4 + r4;
                if (m < M) {
                    float o = oacc[i][j][r4];
                    if (HAS_BO) o = fmaxf(o + bv, 0.0f);
                    if (OUT_BF16)
                        ((unsigned short*)out)[(size_t)m * OUTW + col] = f2b(o);
                    else
                        ((float*)out)[(size_t)m * OUTW + col] = o;
                }
            }
        }
    }
}

static inline int cdiv(long a, long b) { return (int)((a + b - 1) / b); }

extern "C" void kernel_launch(void* const* d_in, const int* in_sizes, int n_in,
                              void* d_out, int out_size, void* d_ws, size_t ws_size,
                              hipStream_t stream) {
    const float* x  = (const float*)d_in[0];
    const int*   ei = (const int*)d_in[1];
    const float* ew = (const float*)d_in[2];
    const float* W1 = (const float*)d_in[3];
    const float* b1 = (const float*)d_in[4];
    const float* W2 = (const float*)d_in[5];
    const float* b2 = (const float*)d_in[6];
    const float* W3 = (const float*)d_in[7];
    const float* b3 = (const float*)d_in[8];
    const float* W4 = (const float*)d_in[9];
    const float* b4 = (const float*)d_in[10];
    const int Nn = in_sizes[0] / 128;   // 50000
    const int E  = in_sizes[1] / 2;     // 800000
    const int* src = ei;
    const int* dst = ei + E;

    char* ws = (char*)d_ws;
    size_t off_b = 0;
    auto alloc = [&](size_t bytes) -> void* {
        void* p = ws + off_b;
        off_b += (bytes + 255) & ~(size_t)255;
        return p;
    };
    float*          dinv   = (float*)alloc((size_t)Nn * 4);
    int*            cnt    = (int*)alloc((size_t)Nn * 4);
    int2*           s_edge = (int2*)alloc((size_t)Nn * ELLW * 8);    // 25.6 MB, (src, w->nrm)
    unsigned short* W1t    = (unsigned short*)alloc(512 * 128 * 2);
    unsigned short* W2t    = (unsigned short*)alloc(128 * 512 * 2);
    unsigned short* W3t    = (unsigned short*)alloc(1024 * 128 * 2);
    unsigned short* W4t    = (unsigned short*)alloc(64 * 1024 * 2);
    unsigned short* xb     = (unsigned short*)alloc((size_t)Nn * 128 * 2);
    unsigned short* t2b    = (unsigned short*)alloc((size_t)Nn * 128 * 2);
    unsigned short* actb   = (unsigned short*)alloc((size_t)Nn * 128 * 2);
    float*          out    = (float*)d_out;

    // zero ELL counters, then merged setup (fill_ell | weights | x->bf16)
    hipMemsetAsync(cnt, 0, (size_t)Nn * 4, stream);
    k_setup<<<10655, 256, 0, stream>>>(x, W1, W2, W3, W4, W1t, W2t, W3t, W4t,
                                       xb, src, dst, ew, cnt, s_edge, Nn, E);
    k_deg<<<cdiv(Nn, 4), 256, 0, stream>>>(s_edge, cnt, dinv, Nn);

    // agg1 = Anorm@x (computes+stores nrm), fused layers 1+2 -> t2 (bf16)
    k_gather<true, false><<<cdiv(Nn, 4), 256, 0, stream>>>(
        xb, s_edge, cnt, dinv, nullptr, actb, Nn);
    k_mlp<512, 128, false, true><<<cdiv(Nn, 128), 256, 0, stream>>>(
        actb, W1t, W2t, b1, nullptr, t2b, Nn);

    // h2 = relu(Anorm@t2 + b2)
    k_gather<false, true><<<cdiv(Nn, 4), 256, 0, stream>>>(
        t2b, s_edge, cnt, dinv, b2, actb, Nn);

    // fused layers 3+4 -> out (fp32)
    k_mlp<1024, 64, true, false><<<cdiv(Nn, 128), 256, 0, stream>>>(
        actb, W3t, W4t, b3, b4, out, Nn);
}